// Round 3
// baseline (528.054 us; speedup 1.0000x reference)
//
#include <hip/hip_runtime.h>
#include <hip/hip_bf16.h>

#define TT 2048
#define HD 1024
#define NE 8
#define ID 2048

typedef short bf16x8 __attribute__((ext_vector_type(8)));
typedef float f32x4 __attribute__((ext_vector_type(4)));

__device__ __forceinline__ unsigned f2bf(float f){
  unsigned u = __float_as_uint(f);
  return (u + 0x7FFFu + ((u >> 16) & 1u)) >> 16;  // RNE, low 16 bits valid
}
__device__ __forceinline__ float gelu_t(float x){
  float x3 = x * x * x;
  return 0.5f * x * (1.f + tanhf(0.7978845608028654f * (x + 0.044715f * x3)));
}

// ---------------- Router: logits -> softcap -> top2 -> softmax -> gather lists
__global__ __launch_bounds__(64) void router_kernel(
    const float* __restrict__ x,    // [T,H] fp32
    const float* __restrict__ gw,   // [H,E] fp32
    int* __restrict__ counts,       // [E]
    int* __restrict__ list_ak,      // [E,T]  (t*2+slot)
    float* __restrict__ wlist)      // [E,T]
{
  int t = blockIdx.x;
  int lane = threadIdx.x;
  float acc[NE];
  #pragma unroll
  for (int e = 0; e < NE; ++e) acc[e] = 0.f;
  const float* xr = x + (size_t)t * HD;
  #pragma unroll
  for (int j = 0; j < HD / 64; ++j) {
    int h = j * 64 + lane;
    float xv = xr[h];
    float4 g0 = *(const float4*)(gw + (size_t)h * NE);
    float4 g1 = *(const float4*)(gw + (size_t)h * NE + 4);
    acc[0] += xv * g0.x; acc[1] += xv * g0.y;
    acc[2] += xv * g0.z; acc[3] += xv * g0.w;
    acc[4] += xv * g1.x; acc[5] += xv * g1.y;
    acc[6] += xv * g1.z; acc[7] += xv * g1.w;
  }
  #pragma unroll
  for (int e = 0; e < NE; ++e) {
    float v = acc[e];
    #pragma unroll
    for (int off = 32; off > 0; off >>= 1) v += __shfl_xor(v, off, 64);
    acc[e] = v;
  }
  if (lane == 0) {
    float lg[NE];
    #pragma unroll
    for (int e = 0; e < NE; ++e) lg[e] = tanhf(acc[e] * (1.0f / 30.0f));
    int i0 = 0;
    #pragma unroll
    for (int e = 1; e < NE; ++e) if (lg[e] > lg[i0]) i0 = e;
    int i1 = (i0 == 0) ? 1 : 0;
    #pragma unroll
    for (int e = 0; e < NE; ++e) if (e != i0 && lg[e] > lg[i1]) i1 = e;
    float e1 = __expf(lg[i1] - lg[i0]);   // <= 1
    float w0 = 1.f / (1.f + e1);
    float w1 = 1.f - w0;
    int p0 = atomicAdd(counts + i0, 1);
    list_ak[i0 * TT + p0] = t * 2;
    wlist[i0 * TT + p0] = w0;
    int p1 = atomicAdd(counts + i1, 1);
    list_ak[i1 * TT + p1] = t * 2 + 1;
    wlist[i1 * TT + p1] = w1;
  }
}

// ---------------- Fused G+U gathered GEMM with act epilogue.
// Tile M=64 x N=128, BK=32. 4 waves, wave w covers n [w*32, w*32+32), full M.
// act[ak, n] = gelu(sum_k x[t,k] Wg[k,n]) * (sum_k x[t,k] Wu[k,n])
__global__ __launch_bounds__(256) void gu_gemm(
    const float* __restrict__ x,         // [T, H]
    const float* __restrict__ wg,        // [E, H, I]
    const float* __restrict__ wu,        // [E, H, I]
    unsigned short* __restrict__ act,    // [T*2, I] bf16
    const int* __restrict__ counts,
    const int* __restrict__ list_ak)
{
  int e = blockIdx.z;
  int nCnt = counts[e];
  int m0 = blockIdx.y * 64;
  if (m0 >= nCnt) return;
  int c0 = blockIdx.x * 128;
  const float* Wg = wg + (size_t)e * HD * ID;
  const float* Wu = wu + (size_t)e * HD * ID;

  __shared__ unsigned short As[64 * 32];   // bf16 [m][k]
  __shared__ unsigned Btg[128 * 20];       // bf16 pairs [n][k/2], padded
  __shared__ unsigned Btu[128 * 20];

  int tid = threadIdx.x;
  int wave = tid >> 6, lane = tid & 63;
  int wn = wave * 32;

  // A staging: 4 threads per row, 8 floats each
  int arow = tid >> 2, aq = tid & 3;
  int apos = m0 + arow;
  long abase = -1;
  if (apos < nCnt) abase = (long)(list_ak[e * TT + apos] >> 1) * HD;
  // B staging: thread covers 8k x 2n; kc in [0,4), nd in [0,64)
  int kc = tid >> 6, nd = tid & 63;

  float4 a0, a1;
  float2 bgv[8], buv[8];

  auto loadTiles = [&](int k0) {
    if (abase >= 0) {
      const float* p = x + abase + k0 + aq * 8;
      a0 = *(const float4*)p;
      a1 = *(const float4*)(p + 4);
    } else {
      a0 = make_float4(0.f, 0.f, 0.f, 0.f);
      a1 = a0;
    }
    const float* pg = Wg + (size_t)(k0 + kc * 8) * ID + c0 + nd * 2;
    const float* pu = Wu + (size_t)(k0 + kc * 8) * ID + c0 + nd * 2;
    #pragma unroll
    for (int j = 0; j < 8; ++j) {
      bgv[j] = *(const float2*)(pg + (size_t)j * ID);
      buv[j] = *(const float2*)(pu + (size_t)j * ID);
    }
  };
  auto storeTiles = [&]() {
    uint4 ov;
    ov.x = f2bf(a0.x) | (f2bf(a0.y) << 16);
    ov.y = f2bf(a0.z) | (f2bf(a0.w) << 16);
    ov.z = f2bf(a1.x) | (f2bf(a1.y) << 16);
    ov.w = f2bf(a1.z) | (f2bf(a1.w) << 16);
    *(uint4*)(&As[arow * 32 + aq * 8]) = ov;
    unsigned lo[4], hi[4];
    #pragma unroll
    for (int jj = 0; jj < 4; ++jj) {
      float2 a = bgv[2 * jj], b = bgv[2 * jj + 1];
      lo[jj] = f2bf(a.x) | (f2bf(b.x) << 16);
      hi[jj] = f2bf(a.y) | (f2bf(b.y) << 16);
    }
    *(uint4*)(&Btg[(nd * 2 + 0) * 20 + kc * 4]) = make_uint4(lo[0], lo[1], lo[2], lo[3]);
    *(uint4*)(&Btg[(nd * 2 + 1) * 20 + kc * 4]) = make_uint4(hi[0], hi[1], hi[2], hi[3]);
    #pragma unroll
    for (int jj = 0; jj < 4; ++jj) {
      float2 a = buv[2 * jj], b = buv[2 * jj + 1];
      lo[jj] = f2bf(a.x) | (f2bf(b.x) << 16);
      hi[jj] = f2bf(a.y) | (f2bf(b.y) << 16);
    }
    *(uint4*)(&Btu[(nd * 2 + 0) * 20 + kc * 4]) = make_uint4(lo[0], lo[1], lo[2], lo[3]);
    *(uint4*)(&Btu[(nd * 2 + 1) * 20 + kc * 4]) = make_uint4(hi[0], hi[1], hi[2], hi[3]);
  };

  f32x4 accg[4][2], accu[4][2];
  f32x4 zed = {0.f, 0.f, 0.f, 0.f};
  #pragma unroll
  for (int i = 0; i < 4; ++i)
    #pragma unroll
    for (int j = 0; j < 2; ++j) { accg[i][j] = zed; accu[i][j] = zed; }

  loadTiles(0);
  for (int k0 = 0; k0 < HD; k0 += 32) {
    storeTiles();
    __syncthreads();
    if (k0 + 32 < HD) loadTiles(k0 + 32);   // in flight during MFMA below

    int q = lane >> 4, l15 = lane & 15;
    bf16x8 af[4], bgf[2], buf_[2];
    #pragma unroll
    for (int mt = 0; mt < 4; ++mt)
      af[mt] = *(const bf16x8*)(&As[(mt * 16 + l15) * 32 + q * 8]);
    #pragma unroll
    for (int nt = 0; nt < 2; ++nt) {
      int col = wn + nt * 16 + l15;
      bgf[nt] = *(const bf16x8*)(&Btg[col * 20 + q * 4]);
      buf_[nt] = *(const bf16x8*)(&Btu[col * 20 + q * 4]);
    }
    #pragma unroll
    for (int mt = 0; mt < 4; ++mt)
      #pragma unroll
      for (int nt = 0; nt < 2; ++nt) {
        accg[mt][nt] = __builtin_amdgcn_mfma_f32_16x16x32_bf16(af[mt], bgf[nt], accg[mt][nt], 0, 0, 0);
        accu[mt][nt] = __builtin_amdgcn_mfma_f32_16x16x32_bf16(af[mt], buf_[nt], accu[mt][nt], 0, 0, 0);
      }
    __syncthreads();
  }

  // epilogue: act = gelu(g) * u, bf16
  int col = lane & 15, rgrp = lane >> 4;
  #pragma unroll
  for (int mt = 0; mt < 4; ++mt) {
    #pragma unroll
    for (int r = 0; r < 4; ++r) {
      int pos = m0 + mt * 16 + rgrp * 4 + r;
      if (pos >= nCnt) continue;
      int ak = list_ak[e * TT + pos];
      #pragma unroll
      for (int nt = 0; nt < 2; ++nt) {
        int ncol = c0 + wn + nt * 16 + col;
        float av = gelu_t(accg[mt][nt][r]) * accu[mt][nt][r];
        act[(size_t)ak * ID + ncol] = (unsigned short)f2bf(av);
      }
    }
  }
}

// ---------------- D GEMM: yw[ak, n] = w[ak] * sum_k act[ak,k] * Wd_e[k,n]
// Tile M=64 x N=128, BK=32, same wave layout as gu_gemm.
__global__ __launch_bounds__(256) void d_gemm(
    const unsigned short* __restrict__ act,  // [T*2, I] bf16
    const float* __restrict__ wd,            // [E, I, H]
    float* __restrict__ yw,                  // [T*2, H] fp32
    const int* __restrict__ counts,
    const int* __restrict__ list_ak,
    const float* __restrict__ wlist)
{
  int e = blockIdx.z;
  int nCnt = counts[e];
  int m0 = blockIdx.y * 64;
  if (m0 >= nCnt) return;
  int c0 = blockIdx.x * 128;
  const float* Wd = wd + (size_t)e * ID * HD;

  __shared__ unsigned short As[64 * 32];
  __shared__ unsigned Bt[128 * 20];

  int tid = threadIdx.x;
  int wave = tid >> 6, lane = tid & 63;
  int wn = wave * 32;

  int arow = tid >> 2, aq = tid & 3;
  int apos = m0 + arow;
  long abase = -1;
  int aak = 0;
  if (apos < nCnt) { aak = list_ak[e * TT + apos]; abase = (long)aak * ID; }
  int kc = tid >> 6, nd = tid & 63;

  uint4 areg;
  float2 bv[8];
  auto loadTiles = [&](int k0) {
    if (abase >= 0)
      areg = *(const uint4*)(act + abase + k0 + aq * 8);
    else
      areg = make_uint4(0u, 0u, 0u, 0u);
    const float* pb = Wd + (size_t)(k0 + kc * 8) * HD + c0 + nd * 2;
    #pragma unroll
    for (int j = 0; j < 8; ++j) bv[j] = *(const float2*)(pb + (size_t)j * HD);
  };
  auto storeTiles = [&]() {
    *(uint4*)(&As[arow * 32 + aq * 8]) = areg;
    unsigned lo[4], hi[4];
    #pragma unroll
    for (int jj = 0; jj < 4; ++jj) {
      float2 a = bv[2 * jj], b = bv[2 * jj + 1];
      lo[jj] = f2bf(a.x) | (f2bf(b.x) << 16);
      hi[jj] = f2bf(a.y) | (f2bf(b.y) << 16);
    }
    *(uint4*)(&Bt[(nd * 2 + 0) * 20 + kc * 4]) = make_uint4(lo[0], lo[1], lo[2], lo[3]);
    *(uint4*)(&Bt[(nd * 2 + 1) * 20 + kc * 4]) = make_uint4(hi[0], hi[1], hi[2], hi[3]);
  };

  f32x4 acc[4][2];
  f32x4 zed = {0.f, 0.f, 0.f, 0.f};
  #pragma unroll
  for (int i = 0; i < 4; ++i)
    #pragma unroll
    for (int j = 0; j < 2; ++j) acc[i][j] = zed;

  loadTiles(0);
  for (int k0 = 0; k0 < ID; k0 += 32) {
    storeTiles();
    __syncthreads();
    if (k0 + 32 < ID) loadTiles(k0 + 32);

    int q = lane >> 4, l15 = lane & 15;
    bf16x8 af[4], bf[2];
    #pragma unroll
    for (int mt = 0; mt < 4; ++mt)
      af[mt] = *(const bf16x8*)(&As[(mt * 16 + l15) * 32 + q * 8]);
    #pragma unroll
    for (int nt = 0; nt < 2; ++nt)
      bf[nt] = *(const bf16x8*)(&Bt[(wn + nt * 16 + l15) * 20 + q * 4]);
    #pragma unroll
    for (int mt = 0; mt < 4; ++mt)
      #pragma unroll
      for (int nt = 0; nt < 2; ++nt)
        acc[mt][nt] = __builtin_amdgcn_mfma_f32_16x16x32_bf16(af[mt], bf[nt], acc[mt][nt], 0, 0, 0);
    __syncthreads();
  }

  int col = lane & 15, rgrp = lane >> 4;
  #pragma unroll
  for (int mt = 0; mt < 4; ++mt) {
    #pragma unroll
    for (int r = 0; r < 4; ++r) {
      int pos = m0 + mt * 16 + rgrp * 4 + r;
      if (pos >= nCnt) continue;
      int ak = list_ak[e * TT + pos];
      float ws = wlist[e * TT + pos];
      #pragma unroll
      for (int nt = 0; nt < 2; ++nt) {
        int ncol = c0 + wn + nt * 16 + col;
        yw[(size_t)ak * HD + ncol] = acc[mt][nt][r] * ws;
      }
    }
  }
}

// ---------------- out[t,h] = yw[2t,h] + yw[2t+1,h]  (fp32)
__global__ void combine_kernel(const float* __restrict__ yw,
                               float* __restrict__ out)
{
  const int total = TT * HD / 4;
  for (int i = blockIdx.x * blockDim.x + threadIdx.x; i < total;
       i += gridDim.x * blockDim.x) {
    int i4 = i * 4;
    int t = i4 >> 10;         // / HD
    int h = i4 & (HD - 1);
    float4 a = *(const float4*)(yw + ((size_t)(2 * t)) * HD + h);
    float4 b = *(const float4*)(yw + ((size_t)(2 * t + 1)) * HD + h);
    float4 o;
    o.x = a.x + b.x; o.y = a.y + b.y; o.z = a.z + b.z; o.w = a.w + b.w;
    *(float4*)(out + (size_t)i4) = o;
  }
}

extern "C" void kernel_launch(void* const* d_in, const int* in_sizes, int n_in,
                              void* d_out, int out_size, void* d_ws, size_t ws_size,
                              hipStream_t stream) {
  const float* x  = (const float*)d_in[0];  // [T,H]
  const float* gw = (const float*)d_in[1];  // [H,E]
  const float* wg = (const float*)d_in[2];  // [E,H,I]
  const float* wu = (const float*)d_in[3];  // [E,H,I]
  const float* wd = (const float*)d_in[4];  // [E,I,H]
  float* out = (float*)d_out;

  char* ws = (char*)d_ws;
  int* counts   = (int*)ws;                       // zeroed below
  int* list_ak  = (int*)(ws + 256);               // 64 KB
  float* wlist  = (float*)(ws + 256 + 65536);     // 64 KB
  size_t off = 256 + 2 * 65536;
  unsigned short* act = (unsigned short*)(ws + off);            // 16 MB bf16 [T*2, I]
  float* yw = (float*)(ws + off + (size_t)TT * 2 * ID * 2);     // 16 MB fp32 [T*2, H]

  hipMemsetAsync(counts, 0, 256, stream);
  router_kernel<<<TT, 64, 0, stream>>>(x, gw, counts, list_ak, wlist);

  dim3 blk(256);
  dim3 gGU(ID / 128, 32, NE);   // (16,32,8); y covers worst-case cnt=2048 at M=64
  gu_gemm<<<gGU, blk, 0, stream>>>(x, wg, wu, act, counts, list_ak);

  dim3 gD(HD / 128, 32, NE);    // (8,32,8)
  d_gemm<<<gD, blk, 0, stream>>>(act, wd, yw, counts, list_ak, wlist);

  combine_kernel<<<1024, 256, 0, stream>>>(yw, out);
}

// Round 5
// 498.338 us; speedup vs baseline: 1.0596x; 1.0596x over previous
//
#include <hip/hip_runtime.h>
#include <hip/hip_bf16.h>

#define TT 2048
#define HD 1024
#define NE 8
#define ID 2048

typedef short bf16x8 __attribute__((ext_vector_type(8)));
typedef float f32x4 __attribute__((ext_vector_type(4)));

#define ASG __attribute__((address_space(1)))
#define ASL __attribute__((address_space(3)))

// async global->LDS, 16B per lane; LDS side = wave-uniform base + lane*16
__device__ __forceinline__ void glds16(const void* g, void* l) {
  __builtin_amdgcn_global_load_lds((ASG const unsigned*)g, (ASL unsigned*)l, 16, 0, 0);
}

__device__ __forceinline__ unsigned f2bf(float f){
  unsigned u = __float_as_uint(f);
  return (u + 0x7FFFu + ((u >> 16) & 1u)) >> 16;  // RNE
}
// pack round(a), round(b) -> dword [bf(a) lo | bf(b) hi]; 3 VALU
__device__ __forceinline__ unsigned packbf(float a, float b){
  return __builtin_amdgcn_perm(__float_as_uint(b) + 0x8000u,
                               __float_as_uint(a) + 0x8000u, 0x07060302u);
}
__device__ __forceinline__ float gelu_t(float x){
  float x3 = x * x * x;
  return 0.5f * x * (1.f + tanhf(0.7978845608028654f * (x + 0.044715f * x3)));
}

// ---------------- Router ----------------
__global__ __launch_bounds__(64) void router_kernel(
    const float* __restrict__ x, const float* __restrict__ gw,
    int* __restrict__ counts, int* __restrict__ list_ak, float* __restrict__ wlist)
{
  int t = blockIdx.x;
  int lane = threadIdx.x;
  float acc[NE];
  #pragma unroll
  for (int e = 0; e < NE; ++e) acc[e] = 0.f;
  const float* xr = x + (size_t)t * HD;
  #pragma unroll
  for (int j = 0; j < HD / 64; ++j) {
    int h = j * 64 + lane;
    float xv = xr[h];
    float4 g0 = *(const float4*)(gw + (size_t)h * NE);
    float4 g1 = *(const float4*)(gw + (size_t)h * NE + 4);
    acc[0] += xv * g0.x; acc[1] += xv * g0.y;
    acc[2] += xv * g0.z; acc[3] += xv * g0.w;
    acc[4] += xv * g1.x; acc[5] += xv * g1.y;
    acc[6] += xv * g1.z; acc[7] += xv * g1.w;
  }
  #pragma unroll
  for (int e = 0; e < NE; ++e) {
    float v = acc[e];
    #pragma unroll
    for (int off = 32; off > 0; off >>= 1) v += __shfl_xor(v, off, 64);
    acc[e] = v;
  }
  if (lane == 0) {
    float lg[NE];
    #pragma unroll
    for (int e = 0; e < NE; ++e) lg[e] = tanhf(acc[e] * (1.0f / 30.0f));
    int i0 = 0;
    #pragma unroll
    for (int e = 1; e < NE; ++e) if (lg[e] > lg[i0]) i0 = e;
    int i1 = (i0 == 0) ? 1 : 0;
    #pragma unroll
    for (int e = 0; e < NE; ++e) if (e != i0 && lg[e] > lg[i1]) i1 = e;
    float e1 = __expf(lg[i1] - lg[i0]);
    float w0 = 1.f / (1.f + e1);
    float w1 = 1.f - w0;
    int p0 = atomicAdd(counts + i0, 1);
    list_ak[i0 * TT + p0] = t * 2;
    wlist[i0 * TT + p0] = w0;
    int p1 = atomicAdd(counts + i1, 1);
    list_ak[i1 * TT + p1] = t * 2 + 1;
    wlist[i1 * TT + p1] = w1;
  }
}

// ---------------- x fp32 -> bf16 ----------------
__global__ void xcvt_kernel(const float* __restrict__ x, unsigned short* __restrict__ xb)
{
  int i = blockIdx.x * blockDim.x + threadIdx.x;   // 8 elems each
  const float* p = x + (size_t)i * 8;
  float4 v0 = *(const float4*)p;
  float4 v1 = *(const float4*)(p + 4);
  uint4 o;
  o.x = f2bf(v0.x) | (f2bf(v0.y) << 16);
  o.y = f2bf(v0.z) | (f2bf(v0.w) << 16);
  o.z = f2bf(v1.x) | (f2bf(v1.y) << 16);
  o.w = f2bf(v1.z) | (f2bf(v1.w) << 16);
  *(uint4*)(xb + (size_t)i * 8) = o;
}

// ---------------- Fused G+U gathered GEMM, act epilogue ----------------
// M=64 x N=128 (cols of both Wg,Wu), BK=32, 4 waves each 64m x 32n.
__global__ __launch_bounds__(256) void gu_gemm(
    const unsigned short* __restrict__ xb,   // [T,H] bf16
    const float* __restrict__ wg, const float* __restrict__ wu,
    unsigned short* __restrict__ act,        // [T*2, I] bf16
    const int* __restrict__ counts, const int* __restrict__ list_ak)
{
  int e = blockIdx.z;
  int nCnt = counts[e];
  int m0 = blockIdx.y * 64;
  if (m0 >= nCnt) return;
  int c0 = blockIdx.x * 128;
  const float* Wg = wg + (size_t)e * HD * ID;
  const float* Wu = wu + (size_t)e * HD * ID;

  __shared__ unsigned short As[64 * 32];   // unpadded: global_load_lds lane-linear
  __shared__ unsigned Btg[128 * 20];       // [n][k-pair dwords], 80B rows
  __shared__ unsigned Btu[128 * 20];

  int tid = threadIdx.x;
  int wave = tid >> 6, lane = tid & 63;
  int wn = wave * 32;

  // A gather: row = tid>>2 (4 lanes/row, 16B chunks), clamped; garbage rows unused
  int arow = tid >> 2;
  int gpos = m0 + arow; if (gpos >= nCnt) gpos = nCnt - 1;
  const unsigned short* aptr =
      xb + (size_t)(list_ak[e * TT + gpos] >> 1) * HD + (tid & 3) * 8;
  unsigned short* aLds = &As[wave * 512];  // wave-uniform LDS base

  int kc = wave, nd = lane;  // B: 8 k-rows x 2 cols per thread

  float2 bgv[8], buv[8];
  auto loadB = [&](int k0) {
    const float* pg = Wg + (size_t)(k0 + kc * 8) * ID + c0 + nd * 2;
    const float* pu = Wu + (size_t)(k0 + kc * 8) * ID + c0 + nd * 2;
    #pragma unroll
    for (int j = 0; j < 8; ++j) {
      bgv[j] = *(const float2*)(pg + (size_t)j * ID);
      buv[j] = *(const float2*)(pu + (size_t)j * ID);
    }
  };
  auto storeB = [&]() {
    unsigned lo[4], hi[4];
    #pragma unroll
    for (int jj = 0; jj < 4; ++jj) {
      lo[jj] = packbf(bgv[2 * jj].x, bgv[2 * jj + 1].x);
      hi[jj] = packbf(bgv[2 * jj].y, bgv[2 * jj + 1].y);
    }
    *(uint4*)(&Btg[(nd * 2 + 0) * 20 + kc * 4]) = make_uint4(lo[0], lo[1], lo[2], lo[3]);
    *(uint4*)(&Btg[(nd * 2 + 1) * 20 + kc * 4]) = make_uint4(hi[0], hi[1], hi[2], hi[3]);
    #pragma unroll
    for (int jj = 0; jj < 4; ++jj) {
      lo[jj] = packbf(buv[2 * jj].x, buv[2 * jj + 1].x);
      hi[jj] = packbf(buv[2 * jj].y, buv[2 * jj + 1].y);
    }
    *(uint4*)(&Btu[(nd * 2 + 0) * 20 + kc * 4]) = make_uint4(lo[0], lo[1], lo[2], lo[3]);
    *(uint4*)(&Btu[(nd * 2 + 1) * 20 + kc * 4]) = make_uint4(hi[0], hi[1], hi[2], hi[3]);
  };

  f32x4 accg[4][2], accu[4][2];
  f32x4 zed = {0.f, 0.f, 0.f, 0.f};
  #pragma unroll
  for (int i = 0; i < 4; ++i)
    #pragma unroll
    for (int j = 0; j < 2; ++j) { accg[i][j] = zed; accu[i][j] = zed; }

  loadB(0);
  for (int k0 = 0; k0 < HD; k0 += 32) {
    glds16(aptr + k0, aLds);   // async A tile (bf16, gathered rows)
    storeB();
    __syncthreads();           // drains vmcnt (A) + lgkm (B)
    if (k0 + 32 < HD) loadB(k0 + 32);

    int q = lane >> 4, l15 = lane & 15;
    bf16x8 af[4], bgf[2], buf_[2];
    #pragma unroll
    for (int mt = 0; mt < 4; ++mt)
      af[mt] = *(const bf16x8*)(&As[(mt * 16 + l15) * 32 + q * 8]);
    #pragma unroll
    for (int nt = 0; nt < 2; ++nt) {
      int col = wn + nt * 16 + l15;
      bgf[nt]  = *(const bf16x8*)(&Btg[col * 20 + q * 4]);
      buf_[nt] = *(const bf16x8*)(&Btu[col * 20 + q * 4]);
    }
    #pragma unroll
    for (int mt = 0; mt < 4; ++mt)
      #pragma unroll
      for (int nt = 0; nt < 2; ++nt) {
        accg[mt][nt] = __builtin_amdgcn_mfma_f32_16x16x32_bf16(af[mt], bgf[nt], accg[mt][nt], 0, 0, 0);
        accu[mt][nt] = __builtin_amdgcn_mfma_f32_16x16x32_bf16(af[mt], buf_[nt], accu[mt][nt], 0, 0, 0);
      }
    __syncthreads();
  }

  int col = lane & 15, rgrp = lane >> 4;
  #pragma unroll
  for (int mt = 0; mt < 4; ++mt) {
    #pragma unroll
    for (int r = 0; r < 4; ++r) {
      int pos = m0 + mt * 16 + rgrp * 4 + r;
      if (pos >= nCnt) continue;
      int ak = list_ak[e * TT + pos];
      #pragma unroll
      for (int nt = 0; nt < 2; ++nt) {
        int ncol = c0 + wn + nt * 16 + col;
        float av = gelu_t(accg[mt][nt][r]) * accu[mt][nt][r];
        act[(size_t)ak * ID + ncol] = (unsigned short)f2bf(av);
      }
    }
  }
}

// ---------------- D GEMM: yw = w * (act @ Wd_e) ----------------
__global__ __launch_bounds__(256) void d_gemm(
    const unsigned short* __restrict__ act,  // [T*2, I] bf16
    const float* __restrict__ wd,            // [E, I, H]
    float* __restrict__ yw,                  // [T*2, H] fp32
    const int* __restrict__ counts, const int* __restrict__ list_ak,
    const float* __restrict__ wlist)
{
  int e = blockIdx.z;
  int nCnt = counts[e];
  int m0 = blockIdx.y * 64;
  if (m0 >= nCnt) return;
  int c0 = blockIdx.x * 128;
  const float* Wd = wd + (size_t)e * ID * HD;

  __shared__ unsigned short As[64 * 32];
  __shared__ unsigned Bt[128 * 20];

  int tid = threadIdx.x;
  int wave = tid >> 6, lane = tid & 63;
  int wn = wave * 32;

  int arow = tid >> 2;
  int gpos = m0 + arow; if (gpos >= nCnt) gpos = nCnt - 1;
  const unsigned short* aptr =
      act + (size_t)list_ak[e * TT + gpos] * ID + (tid & 3) * 8;
  unsigned short* aLds = &As[wave * 512];

  int kc = wave, nd = lane;
  float2 bv[8];
  auto loadB = [&](int k0) {
    const float* pb = Wd + (size_t)(k0 + kc * 8) * HD + c0 + nd * 2;
    #pragma unroll
    for (int j = 0; j < 8; ++j) bv[j] = *(const float2*)(pb + (size_t)j * HD);
  };
  auto storeB = [&]() {
    unsigned lo[4], hi[4];
    #pragma unroll
    for (int jj = 0; jj < 4; ++jj) {
      lo[jj] = packbf(bv[2 * jj].x, bv[2 * jj + 1].x);
      hi[jj] = packbf(bv[2 * jj].y, bv[2 * jj + 1].y);
    }
    *(uint4*)(&Bt[(nd * 2 + 0) * 20 + kc * 4]) = make_uint4(lo[0], lo[1], lo[2], lo[3]);
    *(uint4*)(&Bt[(nd * 2 + 1) * 20 + kc * 4]) = make_uint4(hi[0], hi[1], hi[2], hi[3]);
  };

  f32x4 acc[4][2];
  f32x4 zed = {0.f, 0.f, 0.f, 0.f};
  #pragma unroll
  for (int i = 0; i < 4; ++i)
    #pragma unroll
    for (int j = 0; j < 2; ++j) acc[i][j] = zed;

  loadB(0);
  for (int k0 = 0; k0 < ID; k0 += 32) {
    glds16(aptr + k0, aLds);
    storeB();
    __syncthreads();
    if (k0 + 32 < ID) loadB(k0 + 32);

    int q = lane >> 4, l15 = lane & 15;
    bf16x8 af[4], bf[2];
    #pragma unroll
    for (int mt = 0; mt < 4; ++mt)
      af[mt] = *(const bf16x8*)(&As[(mt * 16 + l15) * 32 + q * 8]);
    #pragma unroll
    for (int nt = 0; nt < 2; ++nt)
      bf[nt] = *(const bf16x8*)(&Bt[(wn + nt * 16 + l15) * 20 + q * 4]);
    #pragma unroll
    for (int mt = 0; mt < 4; ++mt)
      #pragma unroll
      for (int nt = 0; nt < 2; ++nt)
        acc[mt][nt] = __builtin_amdgcn_mfma_f32_16x16x32_bf16(af[mt], bf[nt], acc[mt][nt], 0, 0, 0);
    __syncthreads();
  }

  int col = lane & 15, rgrp = lane >> 4;
  #pragma unroll
  for (int mt = 0; mt < 4; ++mt) {
    #pragma unroll
    for (int r = 0; r < 4; ++r) {
      int pos = m0 + mt * 16 + rgrp * 4 + r;
      if (pos >= nCnt) continue;
      int ak = list_ak[e * TT + pos];
      float ws = wlist[e * TT + pos];
      #pragma unroll
      for (int nt = 0; nt < 2; ++nt) {
        int ncol = c0 + wn + nt * 16 + col;
        yw[(size_t)ak * HD + ncol] = acc[mt][nt][r] * ws;
      }
    }
  }
}

// ---------------- out[t,h] = yw[2t,h] + yw[2t+1,h] ----------------
__global__ void combine_kernel(const float* __restrict__ yw, float* __restrict__ out)
{
  const int total = TT * HD / 4;
  for (int i = blockIdx.x * blockDim.x + threadIdx.x; i < total;
       i += gridDim.x * blockDim.x) {
    int i4 = i * 4;
    int t = i4 >> 10;
    int h = i4 & (HD - 1);
    float4 a = *(const float4*)(yw + ((size_t)(2 * t)) * HD + h);
    float4 b = *(const float4*)(yw + ((size_t)(2 * t + 1)) * HD + h);
    float4 o;
    o.x = a.x + b.x; o.y = a.y + b.y; o.z = a.z + b.z; o.w = a.w + b.w;
    *(float4*)(out + (size_t)i4) = o;
  }
}

extern "C" void kernel_launch(void* const* d_in, const int* in_sizes, int n_in,
                              void* d_out, int out_size, void* d_ws, size_t ws_size,
                              hipStream_t stream) {
  const float* x  = (const float*)d_in[0];
  const float* gw = (const float*)d_in[1];
  const float* wg = (const float*)d_in[2];
  const float* wu = (const float*)d_in[3];
  const float* wd = (const float*)d_in[4];
  float* out = (float*)d_out;

  char* ws = (char*)d_ws;
  int* counts   = (int*)ws;
  int* list_ak  = (int*)(ws + 256);
  float* wlist  = (float*)(ws + 256 + 65536);
  const size_t off_xb  = 256 + 2 * 65536;                 // 131200
  const size_t off_act = off_xb + ((size_t)TT * HD * 2);  // +4 MB
  const size_t off_yw  = off_act + ((size_t)TT * 2 * ID * 2);  // +16 MB
  unsigned short* xb  = (unsigned short*)(ws + off_xb);
  unsigned short* act = (unsigned short*)(ws + off_act);
  float* yw = (float*)(ws + off_yw);                      // 16 MB

  (void)hipMemsetAsync(counts, 0, 256, stream);
  router_kernel<<<TT, 64, 0, stream>>>(x, gw, counts, list_ak, wlist);
  xcvt_kernel<<<TT * HD / 8 / 256, 256, 0, stream>>>(x, xb);

  dim3 blk(256);
  dim3 gGU(ID / 128, 32, NE);
  gu_gemm<<<gGU, blk, 0, stream>>>(xb, wg, wu, act, counts, list_ak);

  dim3 gD(HD / 128, 32, NE);
  d_gemm<<<gD, blk, 0, stream>>>(act, wd, yw, counts, list_ak, wlist);

  combine_kernel<<<1024, 256, 0, stream>>>(yw, out);
}

// Round 6
// 473.115 us; speedup vs baseline: 1.1161x; 1.0533x over previous
//
#include <hip/hip_runtime.h>
#include <hip/hip_bf16.h>

#define TT 2048
#define HD 1024
#define NE 8
#define ID 2048

typedef short bf16x8 __attribute__((ext_vector_type(8)));
typedef float f32x4 __attribute__((ext_vector_type(4)));

__device__ __forceinline__ unsigned f2bf(float f){
  unsigned u = __float_as_uint(f);
  return (u + 0x7FFFu + ((u >> 16) & 1u)) >> 16;  // RNE
}
// pack round(a)->lo16, round(b)->hi16; 3 VALU
__device__ __forceinline__ unsigned packbf(float a, float b){
  return __builtin_amdgcn_perm(__float_as_uint(b) + 0x8000u,
                               __float_as_uint(a) + 0x8000u, 0x07060302u);
}
__device__ __forceinline__ float gelu_t(float x){
  float x3 = x * x * x;
  return 0.5f * x * (1.f + tanhf(0.7978845608028654f * (x + 0.044715f * x3)));
}

// ---------------- Router ----------------
__global__ __launch_bounds__(64) void router_kernel(
    const float* __restrict__ x, const float* __restrict__ gw,
    int* __restrict__ counts, int* __restrict__ list_ak, float* __restrict__ wlist)
{
  int t = blockIdx.x;
  int lane = threadIdx.x;
  float acc[NE];
  #pragma unroll
  for (int e = 0; e < NE; ++e) acc[e] = 0.f;
  const float* xr = x + (size_t)t * HD;
  #pragma unroll
  for (int j = 0; j < HD / 64; ++j) {
    int h = j * 64 + lane;
    float xv = xr[h];
    float4 g0 = *(const float4*)(gw + (size_t)h * NE);
    float4 g1 = *(const float4*)(gw + (size_t)h * NE + 4);
    acc[0] += xv * g0.x; acc[1] += xv * g0.y;
    acc[2] += xv * g0.z; acc[3] += xv * g0.w;
    acc[4] += xv * g1.x; acc[5] += xv * g1.y;
    acc[6] += xv * g1.z; acc[7] += xv * g1.w;
  }
  #pragma unroll
  for (int e = 0; e < NE; ++e) {
    float v = acc[e];
    #pragma unroll
    for (int off = 32; off > 0; off >>= 1) v += __shfl_xor(v, off, 64);
    acc[e] = v;
  }
  if (lane == 0) {
    float lg[NE];
    #pragma unroll
    for (int e = 0; e < NE; ++e) lg[e] = tanhf(acc[e] * (1.0f / 30.0f));
    int i0 = 0;
    #pragma unroll
    for (int e = 1; e < NE; ++e) if (lg[e] > lg[i0]) i0 = e;
    int i1 = (i0 == 0) ? 1 : 0;
    #pragma unroll
    for (int e = 0; e < NE; ++e) if (e != i0 && lg[e] > lg[i1]) i1 = e;
    float e1 = __expf(lg[i1] - lg[i0]);
    float w0 = 1.f / (1.f + e1);
    float w1 = 1.f - w0;
    int p0 = atomicAdd(counts + i0, 1);
    list_ak[i0 * TT + p0] = t * 2;
    wlist[i0 * TT + p0] = w0;
    int p1 = atomicAdd(counts + i1, 1);
    list_ak[i1 * TT + p1] = t * 2 + 1;
    wlist[i1 * TT + p1] = w1;
  }
}

// ---------------- x fp32 -> bf16 ----------------
__global__ void xcvt_kernel(const float* __restrict__ x, unsigned short* __restrict__ xb)
{
  int i = blockIdx.x * blockDim.x + threadIdx.x;   // 8 elems each
  const float* p = x + (size_t)i * 8;
  float4 v0 = *(const float4*)p;
  float4 v1 = *(const float4*)(p + 4);
  uint4 o;
  o.x = f2bf(v0.x) | (f2bf(v0.y) << 16);
  o.y = f2bf(v0.z) | (f2bf(v0.w) << 16);
  o.z = f2bf(v1.x) | (f2bf(v1.y) << 16);
  o.w = f2bf(v1.z) | (f2bf(v1.w) << 16);
  *(uint4*)(xb + (size_t)i * 8) = o;
}

// A LDS: 72B rows (36 shorts) -> frag-read start banks 18*l15 all distinct mod 32
#define AROW 36
// B LDS: 80B rows (20 dwords)
#define BROW 20

// ---------------- Fused G+U gathered GEMM, act epilogue ----------------
// M=64 x N=128, BK=32, 4 waves each 64m x 32n. No global_load_lds anywhere:
// barriers drain lgkm only, so reg-prefetch of the next k-tile stays in
// flight across both barriers (full-iteration latency cover).
__global__ __launch_bounds__(256) void gu_gemm(
    const unsigned short* __restrict__ xb,   // [T,H] bf16
    const float* __restrict__ wg, const float* __restrict__ wu,
    unsigned short* __restrict__ act,        // [T*2, I] bf16
    const int* __restrict__ counts, const int* __restrict__ list_ak)
{
  int e = blockIdx.z;
  int nCnt = counts[e];
  int m0 = blockIdx.y * 64;
  if (m0 >= nCnt) return;
  int c0 = blockIdx.x * 128;
  const float* Wg = wg + (size_t)e * HD * ID;
  const float* Wu = wu + (size_t)e * HD * ID;

  __shared__ unsigned short As[64 * AROW];
  __shared__ unsigned Btg[128 * BROW];
  __shared__ unsigned Btu[128 * BROW];

  int tid = threadIdx.x;
  int wave = tid >> 6, lane = tid & 63;
  int wn = wave * 32;

  // A: 4 lanes/row, 16B each (x already bf16)
  int arow = tid >> 2, aseg = tid & 3;
  int gpos = m0 + arow; if (gpos >= nCnt) gpos = nCnt - 1;  // clamp, row unused
  const unsigned short* aptr =
      xb + (size_t)(list_ak[e * TT + gpos] >> 1) * HD + aseg * 8;

  // B: thread covers 4 cols x 4 k-rows per matrix
  int bn = (tid & 31) * 4;      // col 0..124
  int bk = (tid >> 3) & ~3;     // = (tid>>5)*4 : 0,4,...,28
  bk = (tid >> 5) * 4;

  uint4 av;
  float4 bg[4], bu[4];
  auto loadTiles = [&](int k0) {
    av = *(const uint4*)(aptr + k0);
    const float* pg = Wg + (size_t)(k0 + bk) * ID + c0 + bn;
    const float* pu = Wu + (size_t)(k0 + bk) * ID + c0 + bn;
    #pragma unroll
    for (int i = 0; i < 4; ++i) {
      bg[i] = *(const float4*)(pg + (size_t)i * ID);
      bu[i] = *(const float4*)(pu + (size_t)i * ID);
    }
  };
  auto storeTiles = [&]() {
    *(uint4*)(&As[arow * AROW + aseg * 8]) = av;
    const float* g = (const float*)bg;
    const float* u = (const float*)bu;
    #pragma unroll
    for (int j = 0; j < 4; ++j) {   // col bn+j; float4 index i holds k=bk+i
      uint2 dg, du;
      dg.x = packbf(g[j], g[4 + j]);        // (bk, bk+1)
      dg.y = packbf(g[8 + j], g[12 + j]);   // (bk+2, bk+3)
      du.x = packbf(u[j], u[4 + j]);
      du.y = packbf(u[8 + j], u[12 + j]);
      *(uint2*)(&Btg[(bn + j) * BROW + (bk >> 1)]) = dg;
      *(uint2*)(&Btu[(bn + j) * BROW + (bk >> 1)]) = du;
    }
  };

  f32x4 accg[4][2], accu[4][2];
  f32x4 zed = {0.f, 0.f, 0.f, 0.f};
  #pragma unroll
  for (int i = 0; i < 4; ++i)
    #pragma unroll
    for (int j = 0; j < 2; ++j) { accg[i][j] = zed; accu[i][j] = zed; }

  loadTiles(0);
  for (int k0 = 0; k0 < HD; k0 += 32) {
    storeTiles();                       // waits only on prev loads (vmcnt)
    __syncthreads();                    // lgkm-only drain
    if (k0 + 32 < HD) loadTiles(k0 + 32);  // in flight across next barrier

    int q = lane >> 4, l15 = lane & 15;
    bf16x8 af[4], bgf[2], buf_[2];
    #pragma unroll
    for (int mt = 0; mt < 4; ++mt)
      af[mt] = *(const bf16x8*)(&As[(mt * 16 + l15) * AROW + q * 8]);
    #pragma unroll
    for (int nt = 0; nt < 2; ++nt) {
      int col = wn + nt * 16 + l15;
      bgf[nt]  = *(const bf16x8*)(&Btg[col * BROW + q * 4]);
      buf_[nt] = *(const bf16x8*)(&Btu[col * BROW + q * 4]);
    }
    #pragma unroll
    for (int mt = 0; mt < 4; ++mt)
      #pragma unroll
      for (int nt = 0; nt < 2; ++nt) {
        accg[mt][nt] = __builtin_amdgcn_mfma_f32_16x16x32_bf16(af[mt], bgf[nt], accg[mt][nt], 0, 0, 0);
        accu[mt][nt] = __builtin_amdgcn_mfma_f32_16x16x32_bf16(af[mt], buf_[nt], accu[mt][nt], 0, 0, 0);
      }
    __syncthreads();
  }

  int col = lane & 15, rgrp = lane >> 4;
  #pragma unroll
  for (int mt = 0; mt < 4; ++mt) {
    #pragma unroll
    for (int r = 0; r < 4; ++r) {
      int pos = m0 + mt * 16 + rgrp * 4 + r;
      if (pos >= nCnt) continue;
      int ak = list_ak[e * TT + pos];
      #pragma unroll
      for (int nt = 0; nt < 2; ++nt) {
        int ncol = c0 + wn + nt * 16 + col;
        float avl = gelu_t(accg[mt][nt][r]) * accu[mt][nt][r];
        act[(size_t)ak * ID + ncol] = (unsigned short)f2bf(avl);
      }
    }
  }
}

// ---------------- D GEMM: yw = w * (act @ Wd_e) ----------------
__global__ __launch_bounds__(256) void d_gemm(
    const unsigned short* __restrict__ act,  // [T*2, I] bf16
    const float* __restrict__ wd,            // [E, I, H]
    float* __restrict__ yw,                  // [T*2, H] fp32
    const int* __restrict__ counts, const int* __restrict__ list_ak,
    const float* __restrict__ wlist)
{
  int e = blockIdx.z;
  int nCnt = counts[e];
  int m0 = blockIdx.y * 64;
  if (m0 >= nCnt) return;
  int c0 = blockIdx.x * 128;
  const float* Wd = wd + (size_t)e * ID * HD;

  __shared__ unsigned short As[64 * AROW];
  __shared__ unsigned Bt[128 * BROW];

  int tid = threadIdx.x;
  int wave = tid >> 6, lane = tid & 63;
  int wn = wave * 32;

  int arow = tid >> 2, aseg = tid & 3;
  int gpos = m0 + arow; if (gpos >= nCnt) gpos = nCnt - 1;
  const unsigned short* aptr =
      act + (size_t)list_ak[e * TT + gpos] * ID + aseg * 8;

  int bn = (tid & 31) * 4;
  int bk = (tid >> 5) * 4;

  uint4 av;
  float4 bv[4];
  auto loadTiles = [&](int k0) {
    av = *(const uint4*)(aptr + k0);
    const float* pb = Wd + (size_t)(k0 + bk) * HD + c0 + bn;
    #pragma unroll
    for (int i = 0; i < 4; ++i) bv[i] = *(const float4*)(pb + (size_t)i * HD);
  };
  auto storeTiles = [&]() {
    *(uint4*)(&As[arow * AROW + aseg * 8]) = av;
    const float* b = (const float*)bv;
    #pragma unroll
    for (int j = 0; j < 4; ++j) {
      uint2 d;
      d.x = packbf(b[j], b[4 + j]);
      d.y = packbf(b[8 + j], b[12 + j]);
      *(uint2*)(&Bt[(bn + j) * BROW + (bk >> 1)]) = d;
    }
  };

  f32x4 acc[4][2];
  f32x4 zed = {0.f, 0.f, 0.f, 0.f};
  #pragma unroll
  for (int i = 0; i < 4; ++i)
    #pragma unroll
    for (int j = 0; j < 2; ++j) acc[i][j] = zed;

  loadTiles(0);
  for (int k0 = 0; k0 < ID; k0 += 32) {
    storeTiles();
    __syncthreads();
    if (k0 + 32 < ID) loadTiles(k0 + 32);

    int q = lane >> 4, l15 = lane & 15;
    bf16x8 af[4], bf[2];
    #pragma unroll
    for (int mt = 0; mt < 4; ++mt)
      af[mt] = *(const bf16x8*)(&As[(mt * 16 + l15) * AROW + q * 8]);
    #pragma unroll
    for (int nt = 0; nt < 2; ++nt)
      bf[nt] = *(const bf16x8*)(&Bt[(wn + nt * 16 + l15) * BROW + q * 4]);
    #pragma unroll
    for (int mt = 0; mt < 4; ++mt)
      #pragma unroll
      for (int nt = 0; nt < 2; ++nt)
        acc[mt][nt] = __builtin_amdgcn_mfma_f32_16x16x32_bf16(af[mt], bf[nt], acc[mt][nt], 0, 0, 0);
    __syncthreads();
  }

  int col = lane & 15, rgrp = lane >> 4;
  #pragma unroll
  for (int mt = 0; mt < 4; ++mt) {
    #pragma unroll
    for (int r = 0; r < 4; ++r) {
      int pos = m0 + mt * 16 + rgrp * 4 + r;
      if (pos >= nCnt) continue;
      int ak = list_ak[e * TT + pos];
      float ws = wlist[e * TT + pos];
      #pragma unroll
      for (int nt = 0; nt < 2; ++nt) {
        int ncol = c0 + wn + nt * 16 + col;
        yw[(size_t)ak * HD + ncol] = acc[mt][nt][r] * ws;
      }
    }
  }
}

// ---------------- out[t,h] = yw[2t,h] + yw[2t+1,h] ----------------
__global__ void combine_kernel(const float* __restrict__ yw, float* __restrict__ out)
{
  const int total = TT * HD / 4;
  for (int i = blockIdx.x * blockDim.x + threadIdx.x; i < total;
       i += gridDim.x * blockDim.x) {
    int i4 = i * 4;
    int t = i4 >> 10;
    int h = i4 & (HD - 1);
    float4 a = *(const float4*)(yw + ((size_t)(2 * t)) * HD + h);
    float4 b = *(const float4*)(yw + ((size_t)(2 * t + 1)) * HD + h);
    float4 o;
    o.x = a.x + b.x; o.y = a.y + b.y; o.z = a.z + b.z; o.w = a.w + b.w;
    *(float4*)(out + (size_t)i4) = o;
  }
}

extern "C" void kernel_launch(void* const* d_in, const int* in_sizes, int n_in,
                              void* d_out, int out_size, void* d_ws, size_t ws_size,
                              hipStream_t stream) {
  const float* x  = (const float*)d_in[0];
  const float* gw = (const float*)d_in[1];
  const float* wg = (const float*)d_in[2];
  const float* wu = (const float*)d_in[3];
  const float* wd = (const float*)d_in[4];
  float* out = (float*)d_out;

  char* ws = (char*)d_ws;
  int* counts   = (int*)ws;
  int* list_ak  = (int*)(ws + 256);
  float* wlist  = (float*)(ws + 256 + 65536);
  const size_t off_xb  = 256 + 2 * 65536;
  const size_t off_act = off_xb + ((size_t)TT * HD * 2);        // +4 MB
  const size_t off_yw  = off_act + ((size_t)TT * 2 * ID * 2);   // +16 MB
  unsigned short* xb  = (unsigned short*)(ws + off_xb);
  unsigned short* act = (unsigned short*)(ws + off_act);
  float* yw = (float*)(ws + off_yw);

  (void)hipMemsetAsync(counts, 0, 256, stream);
  router_kernel<<<TT, 64, 0, stream>>>(x, gw, counts, list_ak, wlist);
  xcvt_kernel<<<TT * HD / 8 / 256, 256, 0, stream>>>(x, xb);

  dim3 blk(256);
  dim3 gGU(ID / 128, 32, NE);
  gu_gemm<<<gGU, blk, 0, stream>>>(xb, wg, wu, act, counts, list_ak);

  dim3 gD(HD / 128, 32, NE);
  d_gemm<<<gD, blk, 0, stream>>>(act, wd, yw, counts, list_ak, wlist);

  combine_kernel<<<1024, 256, 0, stream>>>(yw, out);
}